// Round 1
// baseline (163.243 us; speedup 1.0000x reference)
//
#include <hip/hip_runtime.h>
#include <stdint.h>

// Problem dims
#define NB   4096   // batch rows (M)
#define KD   2048   // IN + S   (K)
#define ND   4096   // 4*S      (N, gate-interleaved: n = s*4 + gate)
#define SD   1024   // state size

// GEMM tile
#define BM   128
#define BN   128
#define BK   32

using f32x4  = __attribute__((ext_vector_type(4))) float;
using bf16x8 = __attribute__((ext_vector_type(8))) short;

typedef const __attribute__((address_space(1))) uint32_t* gas_u32;
typedef __attribute__((address_space(3))) uint32_t* las_u32;

__device__ __forceinline__ unsigned short f2bf(float f) {
    union { float f; uint32_t u; } c; c.f = f;
    uint32_t u = c.u;
    // round-to-nearest-even bf16 (inputs are finite; skip NaN path)
    uint32_t r = (u + 0x7fffu + ((u >> 16) & 1u)) >> 16;
    return (unsigned short)r;
}

__device__ __forceinline__ void async_load16(const void* gsrc, void* ldst) {
    __builtin_amdgcn_global_load_lds((gas_u32)gsrc, (las_u32)ldst, 16, 0, 0);
}

// ---------------------------------------------------------------------------
// Pack kernel: fp32 -> bf16, concat [input|old_h] -> Xb[4096][2048],
// reorder weights rows gate-major->interleaved: Wb[n][k] = W[(n&3)*SD + (n>>2)][k]
// biasR[n] = bias[(n&3)*SD + (n>>2)]
// ---------------------------------------------------------------------------
__global__ void pack_kernel(const float* __restrict__ input,
                            const float* __restrict__ old_h,
                            const float* __restrict__ weights,
                            const float* __restrict__ bias,
                            unsigned short* __restrict__ Xb,
                            unsigned short* __restrict__ Wb,
                            float* __restrict__ biasR) {
    const int XCH = NB * (KD / 4);          // chunks of 4 floats
    const int WCH = ND * (KD / 4);
    const int BCH = ND / 4;
    const int total = XCH + WCH + BCH;
    for (int c = blockIdx.x * blockDim.x + threadIdx.x; c < total;
         c += gridDim.x * blockDim.x) {
        if (c < XCH) {
            int b  = c >> 9;                // / (KD/4=512)
            int k  = (c & 511) << 2;
            const float* src = (k < 1024) ? (input + (size_t)b * 1024 + k)
                                          : (old_h + (size_t)b * 1024 + (k - 1024));
            float4 v = *reinterpret_cast<const float4*>(src);
            ushort4 o;
            o.x = f2bf(v.x); o.y = f2bf(v.y); o.z = f2bf(v.z); o.w = f2bf(v.w);
            *reinterpret_cast<ushort4*>(Xb + (size_t)b * KD + k) = o;
        } else if (c < XCH + WCH) {
            int cc = c - XCH;
            int n  = cc >> 9;
            int k  = (cc & 511) << 2;
            int srow = (n & 3) * SD + (n >> 2);
            float4 v = *reinterpret_cast<const float4*>(weights + (size_t)srow * KD + k);
            ushort4 o;
            o.x = f2bf(v.x); o.y = f2bf(v.y); o.z = f2bf(v.z); o.w = f2bf(v.w);
            *reinterpret_cast<ushort4*>(Wb + (size_t)n * KD + k) = o;
        } else {
            int n4 = (c - XCH - WCH) << 2;
            #pragma unroll
            for (int t = 0; t < 4; ++t) {
                int n = n4 + t;
                biasR[n] = bias[(n & 3) * SD + (n >> 2)];
            }
        }
    }
}

// ---------------------------------------------------------------------------
// Fused gates-GEMM + LSTM epilogue.
// gates[m][n] = sum_k Xb[m][k] * Wb[n][k] + biasR[n];  n = 4*s + gate
// f,i,o = sigmoid; g = tanh; new_cell = f*old_cell + i*g; new_h = o*tanh(nc)
// ---------------------------------------------------------------------------
__launch_bounds__(256)
__global__ void lstm_gemm(const unsigned short* __restrict__ Xb,
                          const unsigned short* __restrict__ Wb,
                          const float* __restrict__ biasR,
                          const float* __restrict__ old_cell,
                          float* __restrict__ new_h,
                          float* __restrict__ new_cell) {
    __shared__ unsigned short As[BM * BK];   // 8 KiB
    __shared__ unsigned short Bs[BN * BK];   // 8 KiB

    const int tid  = threadIdx.x;
    const int lane = tid & 63;
    const int wave = tid >> 6;
    const int wrow = wave >> 1;      // 0..1
    const int wcol = wave & 1;       // 0..1
    const int l15  = lane & 15;
    const int krow = lane >> 4;      // 0..3

    const int mblk  = blockIdx.x >> 5;
    const int nblk  = blockIdx.x & 31;
    const int rbase = mblk * BM;
    const int nbase = nblk * BN;

    f32x4 acc[4][4] = {};

    // staging chunk ids: chunk c covers LDS bytes [c*16, c*16+16),
    // i.e. tile row (c>>2), k-subchunk (c&3)*8 bf16
    const int c0 = tid;          // q=0
    const int c1 = 256 + tid;    // q=1
    const int ar0 = c0 >> 2, ak0 = (c0 & 3) * 8;
    const int ar1 = c1 >> 2, ak1 = (c1 & 3) * 8;

    for (int k0 = 0; k0 < KD; k0 += BK) {
        // stage A (X rows) and B (W rows) tiles, 16B per thread per issue
        async_load16(Xb + (size_t)(rbase + ar0) * KD + k0 + ak0, As + c0 * 8);
        async_load16(Xb + (size_t)(rbase + ar1) * KD + k0 + ak1, As + c1 * 8);
        async_load16(Wb + (size_t)(nbase + ar0) * KD + k0 + ak0, Bs + c0 * 8);
        async_load16(Wb + (size_t)(nbase + ar1) * KD + k0 + ak1, Bs + c1 * 8);

        asm volatile("s_waitcnt vmcnt(0)" ::: "memory");
        __syncthreads();

        bf16x8 a[4], b[4];
        #pragma unroll
        for (int i = 0; i < 4; ++i) {
            a[i] = *reinterpret_cast<const bf16x8*>(
                As + (wrow * 64 + i * 16 + l15) * BK + krow * 8);
            b[i] = *reinterpret_cast<const bf16x8*>(
                Bs + (wcol * 64 + i * 16 + l15) * BK + krow * 8);
        }
        #pragma unroll
        for (int i = 0; i < 4; ++i)
            #pragma unroll
            for (int j = 0; j < 4; ++j)
                acc[i][j] = __builtin_amdgcn_mfma_f32_16x16x32_bf16(
                    a[i], b[j], acc[i][j], 0, 0, 0);

        __syncthreads();   // protect LDS before next iteration's staging
    }

    // ---- epilogue ----
    // add (reordered) bias: column n is constant across regs
    #pragma unroll
    for (int j = 0; j < 4; ++j) {
        float bv = biasR[nbase + wcol * 64 + j * 16 + l15];
        #pragma unroll
        for (int i = 0; i < 4; ++i)
            #pragma unroll
            for (int r = 0; r < 4; ++r)
                acc[i][j][r] += bv;
    }

    const bool active = (lane & 3) == 0;   // these lanes own col n = 4*s (f gate)
    #pragma unroll
    for (int i = 0; i < 4; ++i) {
        const int row = rbase + wrow * 64 + i * 16 + krow * 4;   // + r
        #pragma unroll
        for (int j = 0; j < 4; ++j) {
            const int n0 = nbase + wcol * 64 + j * 16;           // + l15
            #pragma unroll
            for (int r = 0; r < 4; ++r) {
                float v  = acc[i][j][r];
                float vi = __shfl_xor(v, 1);
                float vo = __shfl_xor(v, 2);
                float vg = __shfl_xor(v, 3);
                if (active) {
                    int rr = row + r;
                    int s  = (n0 + l15) >> 2;
                    float f  = 1.f / (1.f + __expf(-v));
                    float ig = 1.f / (1.f + __expf(-vi));
                    float og = 1.f / (1.f + __expf(-vo));
                    float gg = tanhf(vg);
                    float oc = old_cell[(size_t)rr * SD + s];
                    float nc = f * oc + ig * gg;
                    float nh = og * tanhf(nc);
                    new_h[(size_t)rr * SD + s]    = nh;
                    new_cell[(size_t)rr * SD + s] = nc;
                }
            }
        }
    }
}

extern "C" void kernel_launch(void* const* d_in, const int* in_sizes, int n_in,
                              void* d_out, int out_size, void* d_ws, size_t ws_size,
                              hipStream_t stream) {
    const float* input    = (const float*)d_in[0];
    const float* old_h    = (const float*)d_in[1];
    const float* old_cell = (const float*)d_in[2];
    const float* weights  = (const float*)d_in[3];
    const float* bias     = (const float*)d_in[4];

    unsigned short* Xb  = (unsigned short*)d_ws;                          // 16 MiB
    unsigned short* Wb  = (unsigned short*)((char*)d_ws + (size_t)16777216); // 16 MiB
    float*          bR  = (float*)((char*)d_ws + (size_t)33554432);       // 16 KiB

    float* out_h = (float*)d_out;
    float* out_c = out_h + (size_t)NB * SD;

    pack_kernel<<<2048, 256, 0, stream>>>(input, old_h, weights, bias, Xb, Wb, bR);
    lstm_gemm<<<(NB / BM) * (ND / BN), 256, 0, stream>>>(Xb, Wb, bR, old_cell,
                                                         out_h, out_c);
}

// Round 2
// 103.163 us; speedup vs baseline: 1.5824x; 1.5824x over previous
//
#include <hip/hip_runtime.h>
#include <stdint.h>

// Problem dims
#define NB   4096   // batch rows (M)
#define KD   2048   // IN + S   (K)
#define ND   4096   // 4*S      (N, reordered: n -> gate=(n>>4)&3, s=(n>>6)*16+(n&15))
#define SD   1024   // state size

// GEMM tile
#define BM   128
#define BN   128
#define BK   64

using f32x4  = __attribute__((ext_vector_type(4))) float;
using bf16x8 = __attribute__((ext_vector_type(8))) short;

typedef const __attribute__((address_space(1))) uint32_t* gas_u32;
typedef __attribute__((address_space(3))) uint32_t* las_u32;

__device__ __forceinline__ unsigned short f2bf(float f) {
    union { float f; uint32_t u; } c; c.f = f;
    uint32_t u = c.u;
    uint32_t r = (u + 0x7fffu + ((u >> 16) & 1u)) >> 16;  // RNE
    return (unsigned short)r;
}

__device__ __forceinline__ void async_load16(const void* gsrc, void* ldst) {
    __builtin_amdgcn_global_load_lds((gas_u32)gsrc, (las_u32)ldst, 16, 0, 0);
}

__device__ __forceinline__ float frcp(float x) { return __builtin_amdgcn_rcpf(x); }
__device__ __forceinline__ float sigm(float x) { return frcp(1.f + __expf(-x)); }
__device__ __forceinline__ float tanh_fast(float x) {
    // 1 - 2/(1+e^{2x}); inf-safe at both ends
    return 1.f - 2.f * frcp(1.f + __expf(2.f * x));
}

// ---------------------------------------------------------------------------
// Pack: fp32 -> bf16, X=[input|old_h]; W rows reordered so GEMM column
// n maps to weights row  gate*SD + (n>>6)*16 + (n&15),  gate=(n>>4)&3.
// (A wave's four 16-col fragments j=0..3 = the 4 gates of the same 16 states.)
// ---------------------------------------------------------------------------
__global__ void pack_kernel(const float* __restrict__ input,
                            const float* __restrict__ old_h,
                            const float* __restrict__ weights,
                            const float* __restrict__ bias,
                            unsigned short* __restrict__ Xb,
                            unsigned short* __restrict__ Wb,
                            float* __restrict__ biasR) {
    const int XCH = NB * (KD / 4);
    const int WCH = ND * (KD / 4);
    const int BCH = ND / 4;
    const int total = XCH + WCH + BCH;
    for (int c = blockIdx.x * blockDim.x + threadIdx.x; c < total;
         c += gridDim.x * blockDim.x) {
        if (c < XCH) {
            int b  = c >> 9;
            int k  = (c & 511) << 2;
            const float* src = (k < 1024) ? (input + (size_t)b * 1024 + k)
                                          : (old_h + (size_t)b * 1024 + (k - 1024));
            float4 v = *reinterpret_cast<const float4*>(src);
            ushort4 o;
            o.x = f2bf(v.x); o.y = f2bf(v.y); o.z = f2bf(v.z); o.w = f2bf(v.w);
            *reinterpret_cast<ushort4*>(Xb + (size_t)b * KD + k) = o;
        } else if (c < XCH + WCH) {
            int cc = c - XCH;
            int n  = cc >> 9;
            int k  = (cc & 511) << 2;
            int srow = ((n >> 4) & 3) * SD + ((n >> 6) * 16 + (n & 15));
            float4 v = *reinterpret_cast<const float4*>(weights + (size_t)srow * KD + k);
            ushort4 o;
            o.x = f2bf(v.x); o.y = f2bf(v.y); o.z = f2bf(v.z); o.w = f2bf(v.w);
            *reinterpret_cast<ushort4*>(Wb + (size_t)n * KD + k) = o;
        } else {
            int n4 = (c - XCH - WCH) << 2;
            #pragma unroll
            for (int t = 0; t < 4; ++t) {
                int n = n4 + t;
                biasR[n] = bias[((n >> 4) & 3) * SD + ((n >> 6) * 16 + (n & 15))];
            }
        }
    }
}

// ---------------------------------------------------------------------------
// Fused gates-GEMM + LSTM epilogue.  BK=64, XOR-swizzled LDS (slot ^= row&7),
// swizzle pre-applied on the global source address (global_load_lds writes
// linearly).  Zero-shuffle epilogue: acc[i][0..3][r] = f,i,o,g of one (row,s).
// ---------------------------------------------------------------------------
__launch_bounds__(256)
__global__ void lstm_gemm(const unsigned short* __restrict__ Xb,
                          const unsigned short* __restrict__ Wb,
                          const float* __restrict__ biasR,
                          const float* __restrict__ old_cell,
                          float* __restrict__ new_h,
                          float* __restrict__ new_cell) {
    __shared__ unsigned short As[BM * BK];   // 16 KiB, row stride 128 B = 32 banks
    __shared__ unsigned short Bs[BN * BK];   // 16 KiB

    const int tid  = threadIdx.x;
    const int lane = tid & 63;
    const int wave = tid >> 6;
    const int wrow = wave >> 1;      // 0..1
    const int wcol = wave & 1;       // 0..1
    const int l15  = lane & 15;
    const int krow = lane >> 4;      // 0..3

    // XCD-aware bijective swizzle (1024 blocks, 8 XCDs)
    const int wg    = blockIdx.x;
    const int swz   = (wg & 7) * 128 + (wg >> 3);
    const int mblk  = swz >> 5;
    const int nblk  = swz & 31;
    const int rbase = mblk * BM;
    const int nbase = nblk * BN;

    f32x4 acc[4][4] = {};

    // staging: tile = 128 rows x 128 B = 1024 16B-chunks; 4 chunks/thread.
    // chunk c -> LDS slot (row=c>>3, pslot=c&7); source k-slot = pslot ^ (row&7)
    int srow_[4], skk_[4];
    #pragma unroll
    for (int q = 0; q < 4; ++q) {
        int c = tid + q * 256;
        srow_[q] = c >> 3;
        skk_[q]  = ((c & 7) ^ (srow_[q] & 7)) * 8;   // element offset within BK
    }

    for (int k0 = 0; k0 < KD; k0 += BK) {
        #pragma unroll
        for (int q = 0; q < 4; ++q)
            async_load16(Xb + (size_t)(rbase + srow_[q]) * KD + k0 + skk_[q],
                         As + (tid + q * 256) * 8);
        #pragma unroll
        for (int q = 0; q < 4; ++q)
            async_load16(Wb + (size_t)(nbase + srow_[q]) * KD + k0 + skk_[q],
                         Bs + (tid + q * 256) * 8);

        asm volatile("s_waitcnt vmcnt(0)" ::: "memory");
        __syncthreads();

        #pragma unroll
        for (int kk = 0; kk < 2; ++kk) {
            bf16x8 a[4], b[4];
            #pragma unroll
            for (int i = 0; i < 4; ++i) {
                int ra = wrow * 64 + i * 16 + l15;
                int sa = (kk * 4 + krow) ^ (ra & 7);
                a[i] = *reinterpret_cast<const bf16x8*>(As + ra * BK + sa * 8);
                int rb = wcol * 64 + i * 16 + l15;
                int sb = (kk * 4 + krow) ^ (rb & 7);
                b[i] = *reinterpret_cast<const bf16x8*>(Bs + rb * BK + sb * 8);
            }
            #pragma unroll
            for (int i = 0; i < 4; ++i)
                #pragma unroll
                for (int j = 0; j < 4; ++j)
                    acc[i][j] = __builtin_amdgcn_mfma_f32_16x16x32_bf16(
                        a[i], b[j], acc[i][j], 0, 0, 0);
        }

        __syncthreads();
    }

    // ---- epilogue: lane owns (rows, state s); gates live in j=0..3 ----
    const int s = ((nbase >> 6) + wcol) * 16 + l15;
    const float b0 = biasR[nbase + wcol * 64 +  0 + l15];
    const float b1 = biasR[nbase + wcol * 64 + 16 + l15];
    const float b2 = biasR[nbase + wcol * 64 + 32 + l15];
    const float b3 = biasR[nbase + wcol * 64 + 48 + l15];

    #pragma unroll
    for (int i = 0; i < 4; ++i) {
        #pragma unroll
        for (int r = 0; r < 4; ++r) {
            const int row = rbase + wrow * 64 + i * 16 + krow * 4 + r;
            float fg = sigm(acc[i][0][r] + b0);
            float ig = sigm(acc[i][1][r] + b1);
            float og = sigm(acc[i][2][r] + b2);
            float gg = tanh_fast(acc[i][3][r] + b3);
            float oc = old_cell[(size_t)row * SD + s];
            float nc = fmaf(fg, oc, ig * gg);
            float nh = og * tanh_fast(nc);
            new_h[(size_t)row * SD + s]    = nh;
            new_cell[(size_t)row * SD + s] = nc;
        }
    }
}

extern "C" void kernel_launch(void* const* d_in, const int* in_sizes, int n_in,
                              void* d_out, int out_size, void* d_ws, size_t ws_size,
                              hipStream_t stream) {
    const float* input    = (const float*)d_in[0];
    const float* old_h    = (const float*)d_in[1];
    const float* old_cell = (const float*)d_in[2];
    const float* weights  = (const float*)d_in[3];
    const float* bias     = (const float*)d_in[4];

    unsigned short* Xb  = (unsigned short*)d_ws;                             // 16 MiB
    unsigned short* Wb  = (unsigned short*)((char*)d_ws + (size_t)16777216); // 16 MiB
    float*          bR  = (float*)((char*)d_ws + (size_t)33554432);          // 16 KiB

    float* out_h = (float*)d_out;
    float* out_c = out_h + (size_t)NB * SD;

    pack_kernel<<<2048, 256, 0, stream>>>(input, old_h, weights, bias, Xb, Wb, bR);
    lstm_gemm<<<(NB / BM) * (ND / BN), 256, 0, stream>>>(Xb, Wb, bR, old_cell,
                                                         out_h, out_c);
}

// Round 3
// 80.660 us; speedup vs baseline: 2.0238x; 1.2790x over previous
//
#include <hip/hip_runtime.h>
#include <stdint.h>

// Problem dims
#define NB   4096   // batch rows (M)
#define KD   2048   // IN + S   (K)
#define ND   4096   // 4*S      (N, reordered: n -> gate=(n>>4)&3, s=(n>>6)*16+(n&15))
#define SD   1024   // state size

// GEMM tile (256x256 8-phase template, 8 waves = 2M x 4N)
#define BM   256
#define BN   256
#define BK   64
#define NKT  (KD / BK)   // 32 K-tiles

using f32x4  = __attribute__((ext_vector_type(4))) float;
using bf16x8 = __attribute__((ext_vector_type(8))) short;

typedef const __attribute__((address_space(1))) uint32_t* gas_u32;
typedef __attribute__((address_space(3))) uint32_t* las_u32;

__device__ __forceinline__ unsigned short f2bf(float f) {
    union { float f; uint32_t u; } c; c.f = f;
    uint32_t u = c.u;
    uint32_t r = (u + 0x7fffu + ((u >> 16) & 1u)) >> 16;  // RNE
    return (unsigned short)r;
}

__device__ __forceinline__ void async_load16(const void* gsrc, void* ldst) {
    __builtin_amdgcn_global_load_lds((gas_u32)gsrc, (las_u32)ldst, 16, 0, 0);
}

__device__ __forceinline__ float frcp(float x) { return __builtin_amdgcn_rcpf(x); }
__device__ __forceinline__ float sigm(float x) { return frcp(1.f + __expf(-x)); }
__device__ __forceinline__ float tanh_fast(float x) {
    return 1.f - 2.f * frcp(1.f + __expf(2.f * x));   // inf-safe
}

// ---------------------------------------------------------------------------
// Pack: fp32 -> bf16, X=[input|old_h]; W rows reordered so GEMM column
// n maps to weights row  gate*SD + (n>>6)*16 + (n&15),  gate=(n>>4)&3.
// ---------------------------------------------------------------------------
__global__ void pack_kernel(const float* __restrict__ input,
                            const float* __restrict__ old_h,
                            const float* __restrict__ weights,
                            const float* __restrict__ bias,
                            unsigned short* __restrict__ Xb,
                            unsigned short* __restrict__ Wb,
                            float* __restrict__ biasR) {
    const int XCH = NB * (KD / 4);
    const int WCH = ND * (KD / 4);
    const int BCH = ND / 4;
    const int total = XCH + WCH + BCH;
    for (int c = blockIdx.x * blockDim.x + threadIdx.x; c < total;
         c += gridDim.x * blockDim.x) {
        if (c < XCH) {
            int b  = c >> 9;
            int k  = (c & 511) << 2;
            const float* src = (k < 1024) ? (input + (size_t)b * 1024 + k)
                                          : (old_h + (size_t)b * 1024 + (k - 1024));
            float4 v = *reinterpret_cast<const float4*>(src);
            ushort4 o;
            o.x = f2bf(v.x); o.y = f2bf(v.y); o.z = f2bf(v.z); o.w = f2bf(v.w);
            *reinterpret_cast<ushort4*>(Xb + (size_t)b * KD + k) = o;
        } else if (c < XCH + WCH) {
            int cc = c - XCH;
            int n  = cc >> 9;
            int k  = (cc & 511) << 2;
            int srow = ((n >> 4) & 3) * SD + ((n >> 6) * 16 + (n & 15));
            float4 v = *reinterpret_cast<const float4*>(weights + (size_t)srow * KD + k);
            ushort4 o;
            o.x = f2bf(v.x); o.y = f2bf(v.y); o.z = f2bf(v.z); o.w = f2bf(v.w);
            *reinterpret_cast<ushort4*>(Wb + (size_t)n * KD + k) = o;
        } else {
            int n4 = (c - XCH - WCH) << 2;
            #pragma unroll
            for (int t = 0; t < 4; ++t) {
                int n = n4 + t;
                biasR[n] = bias[((n >> 4) & 3) * SD + ((n >> 6) * 16 + (n & 15))];
            }
        }
    }
}

// ---------------------------------------------------------------------------
// 256x256 8-phase GEMM + fused LSTM epilogue.
// LDS: [db][A/B][half][128 rows x 64 cols bf16], XOR-swizzled slots.
// Phases = C-quadrants (mq,nq); counted vmcnt(4) at phases 4/8 only.
// Stage slots: p0/p1: t+1.A0/A1 | p2/p3: t+2.B0/B1 | p4/p5: t+2.A0/A1
//              p6/p7: t+3.B0/B1   (each region free >=1 barrier before stage)
// ---------------------------------------------------------------------------
#define SEG(DB, AB, HALF) (((((DB) * 2 + (AB)) * 2) + (HALF)) * 8192)

#define SBAR   __builtin_amdgcn_s_barrier()
#define SFENCE __builtin_amdgcn_sched_barrier(0)
#define ASM_LGKM0  asm volatile("s_waitcnt lgkmcnt(0)" ::: "memory")
#define ASM_VMCNT4 asm volatile("s_waitcnt vmcnt(4)" ::: "memory")

__launch_bounds__(512, 2)
__global__ void lstm_gemm(const unsigned short* __restrict__ Xb,
                          const unsigned short* __restrict__ Wb,
                          const float* __restrict__ biasR,
                          const float* __restrict__ old_cell,
                          float* __restrict__ new_h,
                          float* __restrict__ new_cell) {
    __shared__ unsigned short lds[65536];   // 128 KiB

    const int tid  = threadIdx.x;
    const int lane = tid & 63;
    const int wid  = tid >> 6;       // 0..7
    const int wm   = wid >> 2;       // 0..1  (M half owner)
    const int wn   = wid & 3;        // 0..3  (N quarter owner)
    const int l15  = lane & 15;
    const int krow = lane >> 4;      // 0..3

    // XCD-aware bijective swizzle (256 blocks, 8 XCDs)
    const int wg    = blockIdx.x;
    const int swz   = (wg & 7) * 32 + (wg >> 3);
    const int mblk  = swz >> 4;
    const int nblk  = swz & 15;
    const int rbase = mblk * BM;
    const int nbase = nblk * BN;

    // staging per-thread constants: half-tile = 128 rows x 64 cols = 1024 chunks
    const int c0 = tid, c1 = tid + 512;
    const int srow0 = c0 >> 3, sk0 = ((c0 & 7) ^ (srow0 & 7)) * 8;
    const int srow1 = c1 >> 3, sk1 = ((c1 & 7) ^ (srow1 & 7)) * 8;

    f32x4  acc[8][4] = {};
    bf16x8 a[4][2];        // current mq's A frags (kept across nq phases)
    bf16x8 b[2][2][2];     // [nq][j][kk] (both nq sets kept across mq phases)

#define STAGE(PTR, TB, KT, DB, AB, HALF) do {                                   \
        async_load16((PTR) + (size_t)((TB) + (HALF) * 128 + srow0) * KD +       \
                         (KT) * BK + sk0,                                       \
                     lds + SEG(DB, AB, HALF) + c0 * 8);                         \
        async_load16((PTR) + (size_t)((TB) + (HALF) * 128 + srow1) * KD +       \
                         (KT) * BK + sk1,                                       \
                     lds + SEG(DB, AB, HALF) + c1 * 8);                         \
    } while (0)

#define LOAD_A(DB, MQ) do {                                                     \
        const unsigned short* base_ = lds + SEG(DB, 0, 0) + wm * 8192;          \
        _Pragma("unroll") for (int i_ = 0; i_ < 4; ++i_)                        \
        _Pragma("unroll") for (int kk_ = 0; kk_ < 2; ++kk_) {                   \
            int r_ = (MQ) * 64 + i_ * 16 + l15;                                 \
            int s_ = kk_ * 4 + krow;                                            \
            a[i_][kk_] = *reinterpret_cast<const bf16x8*>(                      \
                base_ + r_ * 64 + ((s_ ^ (r_ & 7)) * 8));                       \
        }                                                                       \
    } while (0)

#define LOAD_B(DB, NQ) do {                                                     \
        const unsigned short* base_ = lds + SEG(DB, 1, 0) + (wn >> 1) * 8192;   \
        _Pragma("unroll") for (int j_ = 0; j_ < 2; ++j_)                        \
        _Pragma("unroll") for (int kk_ = 0; kk_ < 2; ++kk_) {                   \
            int r_ = (wn & 1) * 64 + ((NQ) * 2 + j_) * 16 + l15;                \
            int s_ = kk_ * 4 + krow;                                            \
            b[NQ][j_][kk_] = *reinterpret_cast<const bf16x8*>(                  \
                base_ + r_ * 64 + ((s_ ^ (r_ & 7)) * 8));                       \
        }                                                                       \
    } while (0)

#define MMA(MQ, NQ) do {                                                        \
        _Pragma("unroll") for (int i_ = 0; i_ < 4; ++i_)                        \
        _Pragma("unroll") for (int j_ = 0; j_ < 2; ++j_)                        \
        _Pragma("unroll") for (int kk_ = 0; kk_ < 2; ++kk_)                     \
            acc[(MQ) * 4 + i_][(NQ) * 2 + j_] =                                 \
                __builtin_amdgcn_mfma_f32_16x16x32_bf16(                        \
                    a[i_][kk_], b[NQ][j_][kk_],                                 \
                    acc[(MQ) * 4 + i_][(NQ) * 2 + j_], 0, 0, 0);                \
    } while (0)

#define PH_HEAD  SFENCE; SBAR; ASM_LGKM0; SFENCE; __builtin_amdgcn_s_setprio(1)
#define PH_TAIL  __builtin_amdgcn_s_setprio(0); SFENCE; SBAR; SFENCE
#define PH_TAILV __builtin_amdgcn_s_setprio(0); SFENCE; ASM_VMCNT4; SBAR; SFENCE

    // ---- prologue: tile0 {B0,B1,A0,A1} -> buf0, tile1 {B0,B1} -> buf1 ----
    STAGE(Wb, nbase, 0, 0, 1, 0);
    STAGE(Wb, nbase, 0, 0, 1, 1);
    STAGE(Xb, rbase, 0, 0, 0, 0);
    STAGE(Xb, rbase, 0, 0, 0, 1);
    STAGE(Wb, nbase, 1, 1, 1, 0);
    STAGE(Wb, nbase, 1, 1, 1, 1);
    ASM_VMCNT4;   // tile0's 8 loads landed; tile1.B in flight
    SBAR; SFENCE;

    // ---- main loop: 2 K-tiles per iteration, 8 phases ----
    for (int t = 0; t < NKT; t += 2) {
        const int kt1 = t + 1;
        const int kt2 = (t + 2) & (NKT - 1);
        const int kt3 = (t + 3) & (NKT - 1);

        // p0: tile t (buf0) quadrant (0,0); stage t+1.A0
        LOAD_A(0, 0); LOAD_B(0, 0); STAGE(Xb, rbase, kt1, 1, 0, 0);
        PH_HEAD; MMA(0, 0); PH_TAIL;
        // p1: quadrant (0,1); stage t+1.A1
        LOAD_B(0, 1); STAGE(Xb, rbase, kt1, 1, 0, 1);
        PH_HEAD; MMA(0, 1); PH_TAIL;
        // p2: quadrant (1,0); stage t+2.B0 (buf0.B free after p1)
        LOAD_A(0, 1); STAGE(Wb, nbase, kt2, 0, 1, 0);
        PH_HEAD; MMA(1, 0); PH_TAIL;
        // p3: quadrant (1,1); stage t+2.B1; vmcnt(4) lands all of tile t+1
        STAGE(Wb, nbase, kt2, 0, 1, 1);
        PH_HEAD; MMA(1, 1); PH_TAILV;

        // p4: tile t+1 (buf1) quadrant (0,0); stage t+2.A0 (buf0.A free after p2)
        LOAD_A(1, 0); LOAD_B(1, 0); STAGE(Xb, rbase, kt2, 0, 0, 0);
        PH_HEAD; MMA(0, 0); PH_TAIL;
        // p5: quadrant (0,1); stage t+2.A1
        LOAD_B(1, 1); STAGE(Xb, rbase, kt2, 0, 0, 1);
        PH_HEAD; MMA(0, 1); PH_TAIL;
        // p6: quadrant (1,0); stage t+3.B0 (buf1.B free after p5)
        LOAD_A(1, 1); STAGE(Wb, nbase, kt3, 1, 1, 0);
        PH_HEAD; MMA(1, 0); PH_TAIL;
        // p7: quadrant (1,1); stage t+3.B1; vmcnt(4) lands all of tile t+2
        STAGE(Wb, nbase, kt3, 1, 1, 1);
        PH_HEAD; MMA(1, 1); PH_TAILV;
    }

    // ---- fused LSTM epilogue (reg-resident, zero-shuffle) ----
    const int s = (nblk * 4 + wn) * 16 + l15;
    float bg[4];
    #pragma unroll
    for (int jj = 0; jj < 4; ++jj)
        bg[jj] = biasR[nbase + wn * 64 + jj * 16 + l15];

    #pragma unroll
    for (int mi = 0; mi < 8; ++mi) {
        #pragma unroll
        for (int r = 0; r < 4; ++r) {
            const int row = rbase + wm * 128 + mi * 16 + krow * 4 + r;
            float fg = sigm(acc[mi][0][r] + bg[0]);
            float ig = sigm(acc[mi][1][r] + bg[1]);
            float og = sigm(acc[mi][2][r] + bg[2]);
            float gg = tanh_fast(acc[mi][3][r] + bg[3]);
            float oc = old_cell[(size_t)row * SD + s];
            float nc = fmaf(fg, oc, ig * gg);
            float nh = og * tanh_fast(nc);
            new_h[(size_t)row * SD + s]    = nh;
            new_cell[(size_t)row * SD + s] = nc;
        }
    }
}

extern "C" void kernel_launch(void* const* d_in, const int* in_sizes, int n_in,
                              void* d_out, int out_size, void* d_ws, size_t ws_size,
                              hipStream_t stream) {
    const float* input    = (const float*)d_in[0];
    const float* old_h    = (const float*)d_in[1];
    const float* old_cell = (const float*)d_in[2];
    const float* weights  = (const float*)d_in[3];
    const float* bias     = (const float*)d_in[4];

    unsigned short* Xb  = (unsigned short*)d_ws;                             // 16 MiB
    unsigned short* Wb  = (unsigned short*)((char*)d_ws + (size_t)16777216); // 16 MiB
    float*          bR  = (float*)((char*)d_ws + (size_t)33554432);          // 16 KiB

    float* out_h = (float*)d_out;
    float* out_c = out_h + (size_t)NB * SD;

    pack_kernel<<<2048, 256, 0, stream>>>(input, old_h, weights, bias, Xb, Wb, bR);
    lstm_gemm<<<(NB / BM) * (ND / BN), 512, 0, stream>>>(Xb, Wb, bR, old_cell,
                                                         out_h, out_c);
}

// Round 4
// 79.019 us; speedup vs baseline: 2.0659x; 1.0208x over previous
//
#include <hip/hip_runtime.h>
#include <stdint.h>

// Problem dims
#define NB   4096   // batch rows (M)
#define KD   2048   // IN + S   (K)
#define ND   4096   // 4*S      (N, reordered: n -> gate=(n>>4)&3, s=(n>>6)*16+(n&15))
#define SD   1024   // state size

// GEMM tile (256x256, 8 waves = 2M x 4N, look-ahead-1 frag pipeline)
#define BM   256
#define BN   256
#define BK   64
#define NKT  (KD / BK)   // 32 K-tiles

using f32x4  = __attribute__((ext_vector_type(4))) float;
using bf16x8 = __attribute__((ext_vector_type(8))) short;

typedef const __attribute__((address_space(1))) uint32_t* gas_u32;
typedef __attribute__((address_space(3))) uint32_t* las_u32;

__device__ __forceinline__ unsigned short f2bf(float f) {
    union { float f; uint32_t u; } c; c.f = f;
    uint32_t u = c.u;
    uint32_t r = (u + 0x7fffu + ((u >> 16) & 1u)) >> 16;  // RNE
    return (unsigned short)r;
}

__device__ __forceinline__ void async_load16(const void* gsrc, void* ldst) {
    __builtin_amdgcn_global_load_lds((gas_u32)gsrc, (las_u32)ldst, 16, 0, 0);
}

__device__ __forceinline__ float frcp(float x) { return __builtin_amdgcn_rcpf(x); }
__device__ __forceinline__ float sigm(float x) { return frcp(1.f + __expf(-x)); }
__device__ __forceinline__ float tanh_fast(float x) {
    return 1.f - 2.f * frcp(1.f + __expf(2.f * x));   // inf-safe
}

// ---------------------------------------------------------------------------
// Pack: fp32 -> bf16, X=[input|old_h]; W rows reordered so GEMM column
// n maps to weights row  gate*SD + (n>>6)*16 + (n&15),  gate=(n>>4)&3.
// ---------------------------------------------------------------------------
__global__ void pack_kernel(const float* __restrict__ input,
                            const float* __restrict__ old_h,
                            const float* __restrict__ weights,
                            const float* __restrict__ bias,
                            unsigned short* __restrict__ Xb,
                            unsigned short* __restrict__ Wb,
                            float* __restrict__ biasR) {
    const int XCH = NB * (KD / 4);
    const int WCH = ND * (KD / 4);
    const int BCH = ND / 4;
    const int total = XCH + WCH + BCH;
    for (int c = blockIdx.x * blockDim.x + threadIdx.x; c < total;
         c += gridDim.x * blockDim.x) {
        if (c < XCH) {
            int b  = c >> 9;
            int k  = (c & 511) << 2;
            const float* src = (k < 1024) ? (input + (size_t)b * 1024 + k)
                                          : (old_h + (size_t)b * 1024 + (k - 1024));
            float4 v = *reinterpret_cast<const float4*>(src);
            ushort4 o;
            o.x = f2bf(v.x); o.y = f2bf(v.y); o.z = f2bf(v.z); o.w = f2bf(v.w);
            *reinterpret_cast<ushort4*>(Xb + (size_t)b * KD + k) = o;
        } else if (c < XCH + WCH) {
            int cc = c - XCH;
            int n  = cc >> 9;
            int k  = (cc & 511) << 2;
            int srow = ((n >> 4) & 3) * SD + ((n >> 6) * 16 + (n & 15));
            float4 v = *reinterpret_cast<const float4*>(weights + (size_t)srow * KD + k);
            ushort4 o;
            o.x = f2bf(v.x); o.y = f2bf(v.y); o.z = f2bf(v.z); o.w = f2bf(v.w);
            *reinterpret_cast<ushort4*>(Wb + (size_t)n * KD + k) = o;
        } else {
            int n4 = (c - XCH - WCH) << 2;
            #pragma unroll
            for (int t = 0; t < 4; ++t) {
                int n = n4 + t;
                biasR[n] = bias[((n >> 4) & 3) * SD + ((n >> 6) * 16 + (n & 15))];
            }
        }
    }
}

// ---------------------------------------------------------------------------
// 256x256 GEMM + fused LSTM epilogue; 4 phases/K-tile, look-ahead-1 frags:
//   q0: STAGE A0(t+1); [bar] MMA(mq0,Bm) | read Balt<-B(nq1,cur)
//   q1: STAGE A1(t+1); [bar] MMA(mq0,Balt) | read A<-A(mq1,cur)     (in place)
//   q2: STAGE B0(t+2); [vmcnt(2)+bar] MMA(mq1,Bm) | read Bm<-B(nq0,next)
//   q3: STAGE B1(t+2); [bar] MMA(mq1,Balt) | read A<-A(mq0,next)
// Reads drain under the MFMA cluster; next head's lgkmcnt(0) sees them done.
// vmcnt(2) BEFORE the barrier so all waves' staging landed before next-buf reads.
// ---------------------------------------------------------------------------
#define SEG(DB, AB, HALF) (((((DB) * 2 + (AB)) * 2) + (HALF)) * 8192)

#define SBAR   __builtin_amdgcn_s_barrier()
#define SFENCE __builtin_amdgcn_sched_barrier(0)
#define ASM_LGKM0  asm volatile("s_waitcnt lgkmcnt(0)" ::: "memory")
#define ASM_VMCNT2 asm volatile("s_waitcnt vmcnt(2)" ::: "memory")
#define ASM_VMCNT4 asm volatile("s_waitcnt vmcnt(4)" ::: "memory")

__launch_bounds__(512, 2)
__global__ void lstm_gemm(const unsigned short* __restrict__ Xb,
                          const unsigned short* __restrict__ Wb,
                          const float* __restrict__ biasR,
                          const float* __restrict__ old_cell,
                          float* __restrict__ new_h,
                          float* __restrict__ new_cell) {
    __shared__ unsigned short lds[65536];   // 128 KiB

    const int tid  = threadIdx.x;
    const int lane = tid & 63;
    const int wid  = tid >> 6;       // 0..7
    const int wm   = wid >> 2;       // 0..1  (M half owner)
    const int wn   = wid & 3;        // 0..3  (N quarter owner)
    const int l15  = lane & 15;
    const int krow = lane >> 4;      // 0..3

    // XCD-aware bijective swizzle (256 blocks, 8 XCDs)
    const int wg    = blockIdx.x;
    const int swz   = (wg & 7) * 32 + (wg >> 3);
    const int mblk  = swz >> 4;
    const int nblk  = swz & 15;
    const int rbase = mblk * BM;
    const int nbase = nblk * BN;

    // staging per-thread constants: half-tile = 128 rows x 64 cols = 1024 chunks
    const int c0 = tid, c1 = tid + 512;
    const int srow0 = c0 >> 3, sk0 = ((c0 & 7) ^ (srow0 & 7)) * 8;
    const int srow1 = c1 >> 3, sk1 = ((c1 & 7) ^ (srow1 & 7)) * 8;

    f32x4  acc[8][4] = {};
    bf16x8 a[4][2];        // current A quadrant (reloaded in place)
    bf16x8 bm[2][2];       // B cols 0-31 of wave panel (nq=0)
    bf16x8 ba[2][2];       // B cols 32-63 (nq=1)

#define STAGE(PTR, TB, KT, DB, AB, HALF) do {                                   \
        async_load16((PTR) + (size_t)((TB) + (HALF) * 128 + srow0) * KD +       \
                         (KT) * BK + sk0,                                       \
                     lds + SEG(DB, AB, HALF) + c0 * 8);                         \
        async_load16((PTR) + (size_t)((TB) + (HALF) * 128 + srow1) * KD +       \
                         (KT) * BK + sk1,                                       \
                     lds + SEG(DB, AB, HALF) + c1 * 8);                         \
    } while (0)

#define LOAD_A(DB, MQ) do {                                                     \
        const unsigned short* base_ = lds + SEG(DB, 0, 0) + wm * 8192;          \
        _Pragma("unroll") for (int i_ = 0; i_ < 4; ++i_)                        \
        _Pragma("unroll") for (int kk_ = 0; kk_ < 2; ++kk_) {                   \
            int r_ = (MQ) * 64 + i_ * 16 + l15;                                 \
            int s_ = kk_ * 4 + krow;                                            \
            a[i_][kk_] = *reinterpret_cast<const bf16x8*>(                      \
                base_ + r_ * 64 + ((s_ ^ (r_ & 7)) * 8));                       \
        }                                                                       \
    } while (0)

#define LOAD_B_TO(DST, DB, NQ) do {                                             \
        const unsigned short* base_ = lds + SEG(DB, 1, 0) + (wn >> 1) * 8192;   \
        _Pragma("unroll") for (int j_ = 0; j_ < 2; ++j_)                        \
        _Pragma("unroll") for (int kk_ = 0; kk_ < 2; ++kk_) {                   \
            int r_ = (wn & 1) * 64 + ((NQ) * 2 + j_) * 16 + l15;                \
            int s_ = kk_ * 4 + krow;                                            \
            DST[j_][kk_] = *reinterpret_cast<const bf16x8*>(                    \
                base_ + r_ * 64 + ((s_ ^ (r_ & 7)) * 8));                       \
        }                                                                       \
    } while (0)

#define MMA_Q(MQ, NQH, BB) do {                                                 \
        _Pragma("unroll") for (int i_ = 0; i_ < 4; ++i_)                        \
        _Pragma("unroll") for (int j_ = 0; j_ < 2; ++j_)                        \
        _Pragma("unroll") for (int kk_ = 0; kk_ < 2; ++kk_)                     \
            acc[(MQ) * 4 + i_][(NQH) * 2 + j_] =                                \
                __builtin_amdgcn_mfma_f32_16x16x32_bf16(                        \
                    a[i_][kk_], BB[j_][kk_],                                    \
                    acc[(MQ) * 4 + i_][(NQH) * 2 + j_], 0, 0, 0);               \
    } while (0)

#define PH_HEAD   SFENCE; SBAR; ASM_LGKM0; SFENCE; __builtin_amdgcn_s_setprio(1)
#define PH_HEADV  SFENCE; ASM_VMCNT2; SBAR; ASM_LGKM0; SFENCE; __builtin_amdgcn_s_setprio(1)
#define PH_TAIL   __builtin_amdgcn_s_setprio(0); SFENCE; SBAR; SFENCE

    // ---- prologue: tile0 {B,A} -> buf0, tile1 {B} -> buf1; preload frags ----
    STAGE(Wb, nbase, 0, 0, 1, 0);
    STAGE(Wb, nbase, 0, 0, 1, 1);
    STAGE(Xb, rbase, 0, 0, 0, 0);
    STAGE(Xb, rbase, 0, 0, 0, 1);
    STAGE(Wb, nbase, 1, 1, 1, 0);
    STAGE(Wb, nbase, 1, 1, 1, 1);
    ASM_VMCNT4;   // tile0's 8 loads landed; tile1.B in flight
    SBAR; SFENCE;
    LOAD_B_TO(bm, 0, 0);
    LOAD_A(0, 0);

    // ---- main loop: one K-tile per KBODY, buf compile-time ----
#define KBODY(TT, BUF) do {                                                     \
        const int kt1_ = ((TT) + 1) & (NKT - 1);                                \
        const int kt2_ = ((TT) + 2) & (NKT - 1);                                \
        STAGE(Xb, rbase, kt1_, (BUF) ^ 1, 0, 0);                                \
        PH_HEAD;  MMA_Q(0, 0, bm); LOAD_B_TO(ba, BUF, 1);      PH_TAIL;         \
        STAGE(Xb, rbase, kt1_, (BUF) ^ 1, 0, 1);                                \
        PH_HEAD;  MMA_Q(0, 1, ba); LOAD_A(BUF, 1);             PH_TAIL;         \
        STAGE(Wb, nbase, kt2_, BUF, 1, 0);                                      \
        PH_HEADV; MMA_Q(1, 0, bm); LOAD_B_TO(bm, (BUF) ^ 1, 0); PH_TAIL;        \
        STAGE(Wb, nbase, kt2_, BUF, 1, 1);                                      \
        PH_HEAD;  MMA_Q(1, 1, ba); LOAD_A((BUF) ^ 1, 0);       PH_TAIL;         \
    } while (0)

    for (int t = 0; t < NKT; t += 2) {
        KBODY(t, 0);
        KBODY(t + 1, 1);
    }

    // ---- fused LSTM epilogue (reg-resident, zero-shuffle) ----
    const int s = (nblk * 4 + wn) * 16 + l15;
    float bg[4];
    #pragma unroll
    for (int jj = 0; jj < 4; ++jj)
        bg[jj] = biasR[nbase + wn * 64 + jj * 16 + l15];

    #pragma unroll
    for (int mi = 0; mi < 8; ++mi) {
        #pragma unroll
        for (int r = 0; r < 4; ++r) {
            const int row = rbase + wm * 128 + mi * 16 + krow * 4 + r;
            float fg = sigm(acc[mi][0][r] + bg[0]);
            float ig = sigm(acc[mi][1][r] + bg[1]);
            float og = sigm(acc[mi][2][r] + bg[2]);
            float gg = tanh_fast(acc[mi][3][r] + bg[3]);
            float oc = old_cell[(size_t)row * SD + s];
            float nc = fmaf(fg, oc, ig * gg);
            float nh = og * tanh_fast(nc);
            new_h[(size_t)row * SD + s]    = nh;
            new_cell[(size_t)row * SD + s] = nc;
        }
    }
}

extern "C" void kernel_launch(void* const* d_in, const int* in_sizes, int n_in,
                              void* d_out, int out_size, void* d_ws, size_t ws_size,
                              hipStream_t stream) {
    const float* input    = (const float*)d_in[0];
    const float* old_h    = (const float*)d_in[1];
    const float* old_cell = (const float*)d_in[2];
    const float* weights  = (const float*)d_in[3];
    const float* bias     = (const float*)d_in[4];

    unsigned short* Xb  = (unsigned short*)d_ws;                             // 16 MiB
    unsigned short* Wb  = (unsigned short*)((char*)d_ws + (size_t)16777216); // 16 MiB
    float*          bR  = (float*)((char*)d_ws + (size_t)33554432);          // 16 KiB

    float* out_h = (float*)d_out;
    float* out_c = out_h + (size_t)NB * SD;

    pack_kernel<<<2048, 256, 0, stream>>>(input, old_h, weights, bias, Xb, Wb, bR);
    lstm_gemm<<<(NB / BM) * (ND / BN), 512, 0, stream>>>(Xb, Wb, bR, old_cell,
                                                         out_h, out_c);
}

// Round 5
// 77.267 us; speedup vs baseline: 2.1127x; 1.0227x over previous
//
#include <hip/hip_runtime.h>
#include <stdint.h>

// Problem dims
#define NB   4096   // batch rows (M)
#define KD   2048   // IN + S   (K)
#define ND   4096   // 4*S      (N, reordered: n -> gate=(n>>4)&3, s=(n>>6)*16+(n&15))
#define SD   1024   // state size

// GEMM tile (256x256, 8 waves = 2M x 4N, deep-staged 4-phase pipeline)
#define BM   256
#define BN   256
#define BK   64
#define NKT  (KD / BK)   // 32 K-tiles

using f32x4  = __attribute__((ext_vector_type(4))) float;
using bf16x8 = __attribute__((ext_vector_type(8))) short;

typedef const __attribute__((address_space(1))) uint32_t* gas_u32;
typedef __attribute__((address_space(3))) uint32_t* las_u32;

__device__ __forceinline__ unsigned short f2bf(float f) {
    union { float f; uint32_t u; } c; c.f = f;
    uint32_t u = c.u;
    uint32_t r = (u + 0x7fffu + ((u >> 16) & 1u)) >> 16;  // RNE
    return (unsigned short)r;
}

__device__ __forceinline__ void async_load16(const void* gsrc, void* ldst) {
    __builtin_amdgcn_global_load_lds((gas_u32)gsrc, (las_u32)ldst, 16, 0, 0);
}

__device__ __forceinline__ float frcp(float x) { return __builtin_amdgcn_rcpf(x); }
__device__ __forceinline__ float sigm(float x) { return frcp(1.f + __expf(-x)); }
__device__ __forceinline__ float tanh_fast(float x) {
    return 1.f - 2.f * frcp(1.f + __expf(2.f * x));   // inf-safe
}

// ---------------------------------------------------------------------------
// Pack: fp32 -> bf16, X=[input|old_h]; W rows reordered so GEMM column
// n maps to weights row  gate*SD + (n>>6)*16 + (n&15),  gate=(n>>4)&3.
// ---------------------------------------------------------------------------
__global__ void pack_kernel(const float* __restrict__ input,
                            const float* __restrict__ old_h,
                            const float* __restrict__ weights,
                            const float* __restrict__ bias,
                            unsigned short* __restrict__ Xb,
                            unsigned short* __restrict__ Wb,
                            float* __restrict__ biasR) {
    const int XCH = NB * (KD / 4);
    const int WCH = ND * (KD / 4);
    const int BCH = ND / 4;
    const int total = XCH + WCH + BCH;
    for (int c = blockIdx.x * blockDim.x + threadIdx.x; c < total;
         c += gridDim.x * blockDim.x) {
        if (c < XCH) {
            int b  = c >> 9;
            int k  = (c & 511) << 2;
            const float* src = (k < 1024) ? (input + (size_t)b * 1024 + k)
                                          : (old_h + (size_t)b * 1024 + (k - 1024));
            float4 v = *reinterpret_cast<const float4*>(src);
            ushort4 o;
            o.x = f2bf(v.x); o.y = f2bf(v.y); o.z = f2bf(v.z); o.w = f2bf(v.w);
            *reinterpret_cast<ushort4*>(Xb + (size_t)b * KD + k) = o;
        } else if (c < XCH + WCH) {
            int cc = c - XCH;
            int n  = cc >> 9;
            int k  = (cc & 511) << 2;
            int srow = ((n >> 4) & 3) * SD + ((n >> 6) * 16 + (n & 15));
            float4 v = *reinterpret_cast<const float4*>(weights + (size_t)srow * KD + k);
            ushort4 o;
            o.x = f2bf(v.x); o.y = f2bf(v.y); o.z = f2bf(v.z); o.w = f2bf(v.w);
            *reinterpret_cast<ushort4*>(Wb + (size_t)n * KD + k) = o;
        } else {
            int n4 = (c - XCH - WCH) << 2;
            #pragma unroll
            for (int t = 0; t < 4; ++t) {
                int n = n4 + t;
                biasR[n] = bias[((n >> 4) & 3) * SD + ((n >> 6) * 16 + (n & 15))];
            }
        }
    }
}

// ---------------------------------------------------------------------------
// 256x256 GEMM + fused LSTM epilogue; 4 phases/K-tile, ONE barrier/phase,
// look-ahead-1 frag reads, DEEP staging (3-5 phase issue->gate lead):
//   q0: [bar] MMA(mq0,bm) | read ba<-B(t).nq1          | stage: none
//   q1: [bar] MMA(mq0,ba) | read a <-A(t).mq1          | stage B(t+2).B0
//   q2: [lgkm+vmcnt2+bar] MMA(mq1,bm) | read bm<-B(t+1).nq0 | stage B(t+2).B1, A(t+2).A0
//   q3: [bar] MMA(mq1,ba) | read a <-A(t+1).mq0        | stage A(t+2).A1
// lgkmcnt(0) BEFORE s_barrier: all waves' reads of a region complete before
// any wave can pass the barrier and issue a stage that overwrites it.
// Region-hazard matrix: B(t) last read q0(t) -> staged q1(t)-end (1 bar apart);
// A(t) last read q1(t) -> staged q2/q3(t)-end. vmcnt(2) at q2 head: FIFO
// [B(t+1).B0 x2, B(t+1).B1+A(t+1).A0 x4, A(t+1).A1 x2, B(t+2).B0 x2]=10,
// drain 8 -> exactly tile t+1 landed before its first read (q2/q3).
// ---------------------------------------------------------------------------
#define SEG(DB, AB, HALF) (((((DB) * 2 + (AB)) * 2) + (HALF)) * 8192)

#define SBAR   __builtin_amdgcn_s_barrier()
#define SFENCE __builtin_amdgcn_sched_barrier(0)
#define ASM_LGKM0  asm volatile("s_waitcnt lgkmcnt(0)" ::: "memory")
#define ASM_VMCNT2 asm volatile("s_waitcnt vmcnt(2)" ::: "memory")
#define ASM_VMCNT8 asm volatile("s_waitcnt vmcnt(8)" ::: "memory")

__launch_bounds__(512, 2)
__global__ void lstm_gemm(const unsigned short* __restrict__ Xb,
                          const unsigned short* __restrict__ Wb,
                          const float* __restrict__ biasR,
                          const float* __restrict__ old_cell,
                          float* __restrict__ new_h,
                          float* __restrict__ new_cell) {
    __shared__ unsigned short lds[65536];   // 128 KiB

    const int tid  = threadIdx.x;
    const int lane = tid & 63;
    const int wid  = tid >> 6;       // 0..7
    const int wm   = wid >> 2;       // 0..1  (M half owner)
    const int wn   = wid & 3;        // 0..3  (N quarter owner)
    const int l15  = lane & 15;
    const int krow = lane >> 4;      // 0..3

    // XCD-aware bijective swizzle (256 blocks, 8 XCDs)
    const int wg    = blockIdx.x;
    const int swz   = (wg & 7) * 32 + (wg >> 3);
    const int mblk  = swz >> 4;
    const int nblk  = swz & 15;
    const int rbase = mblk * BM;
    const int nbase = nblk * BN;

    // staging per-thread constants: half-tile = 128 rows x 64 cols = 1024 chunks
    const int c0 = tid, c1 = tid + 512;
    const int srow0 = c0 >> 3, sk0 = ((c0 & 7) ^ (srow0 & 7)) * 8;
    const int srow1 = c1 >> 3, sk1 = ((c1 & 7) ^ (srow1 & 7)) * 8;

    f32x4  acc[8][4] = {};
    bf16x8 a[4][2];        // current A quadrant (renamed in place)
    bf16x8 bm[2][2];       // B wave-panel cols 0-31 (nq=0)
    bf16x8 ba[2][2];       // B wave-panel cols 32-63 (nq=1)

#define STAGE(PTR, TB, KT, DB, AB, HALF) do {                                   \
        async_load16((PTR) + (size_t)((TB) + (HALF) * 128 + srow0) * KD +       \
                         (KT) * BK + sk0,                                       \
                     lds + SEG(DB, AB, HALF) + c0 * 8);                         \
        async_load16((PTR) + (size_t)((TB) + (HALF) * 128 + srow1) * KD +       \
                         (KT) * BK + sk1,                                       \
                     lds + SEG(DB, AB, HALF) + c1 * 8);                         \
    } while (0)

#define LOAD_A(DB, MQ) do {                                                     \
        const unsigned short* base_ = lds + SEG(DB, 0, 0) + wm * 8192;          \
        _Pragma("unroll") for (int i_ = 0; i_ < 4; ++i_)                        \
        _Pragma("unroll") for (int kk_ = 0; kk_ < 2; ++kk_) {                   \
            int r_ = (MQ) * 64 + i_ * 16 + l15;                                 \
            int s_ = kk_ * 4 + krow;                                            \
            a[i_][kk_] = *reinterpret_cast<const bf16x8*>(                      \
                base_ + r_ * 64 + ((s_ ^ (r_ & 7)) * 8));                       \
        }                                                                       \
    } while (0)

#define LOAD_B_TO(DST, DB, NQ) do {                                             \
        const unsigned short* base_ = lds + SEG(DB, 1, 0) + (wn >> 1) * 8192;   \
        _Pragma("unroll") for (int j_ = 0; j_ < 2; ++j_)                        \
        _Pragma("unroll") for (int kk_ = 0; kk_ < 2; ++kk_) {                   \
            int r_ = (wn & 1) * 64 + ((NQ) * 2 + j_) * 16 + l15;                \
            int s_ = kk_ * 4 + krow;                                            \
            DST[j_][kk_] = *reinterpret_cast<const bf16x8*>(                    \
                base_ + r_ * 64 + ((s_ ^ (r_ & 7)) * 8));                       \
        }                                                                       \
    } while (0)

#define MMA_Q(MQ, NQH, BB) do {                                                 \
        _Pragma("unroll") for (int i_ = 0; i_ < 4; ++i_)                        \
        _Pragma("unroll") for (int j_ = 0; j_ < 2; ++j_)                        \
        _Pragma("unroll") for (int kk_ = 0; kk_ < 2; ++kk_)                     \
            acc[(MQ) * 4 + i_][(NQH) * 2 + j_] =                                \
                __builtin_amdgcn_mfma_f32_16x16x32_bf16(                        \
                    a[i_][kk_], BB[j_][kk_],                                    \
                    acc[(MQ) * 4 + i_][(NQH) * 2 + j_], 0, 0, 0);               \
    } while (0)

    // one barrier per phase; lgkm drained BEFORE barrier (cross-wave guarantee)
#define PH_HEAD   SFENCE; ASM_LGKM0; SBAR; SFENCE; __builtin_amdgcn_s_setprio(1)
#define PH_HEADV  SFENCE; ASM_LGKM0; ASM_VMCNT2; SBAR; SFENCE; __builtin_amdgcn_s_setprio(1)
#define PRIO0     __builtin_amdgcn_s_setprio(0)

    // ---- prologue: tiles 0,1 fully staged in steady-state FIFO order ----
    STAGE(Wb, nbase, 0, 0, 1, 0);
    STAGE(Wb, nbase, 0, 0, 1, 1);
    STAGE(Xb, rbase, 0, 0, 0, 0);
    STAGE(Xb, rbase, 0, 0, 0, 1);
    STAGE(Wb, nbase, 1, 1, 1, 0);
    STAGE(Wb, nbase, 1, 1, 1, 1);
    STAGE(Xb, rbase, 1, 1, 0, 0);
    STAGE(Xb, rbase, 1, 1, 0, 1);
    ASM_VMCNT8;   // tile0's 8 loads landed; tile1 (8) in flight
    SBAR; SFENCE;
    LOAD_B_TO(bm, 0, 0);
    LOAD_A(0, 0);

    // ---- main loop: one K-tile per KBODY; stages target tile t+2 ----
#define KBODY(TT, BUF) do {                                                     \
        const int kt2_ = ((TT) + 2) & (NKT - 1);                                \
        /* q0 */                                                                \
        PH_HEAD;  MMA_Q(0, 0, bm); LOAD_B_TO(ba, BUF, 1);       PRIO0;          \
        /* q1 */                                                                \
        PH_HEAD;  MMA_Q(0, 1, ba); LOAD_A(BUF, 1);              PRIO0;          \
        STAGE(Wb, nbase, kt2_, BUF, 1, 0);                                      \
        /* q2 */                                                                \
        PH_HEADV; MMA_Q(1, 0, bm); LOAD_B_TO(bm, (BUF) ^ 1, 0); PRIO0;          \
        STAGE(Wb, nbase, kt2_, BUF, 1, 1);                                      \
        STAGE(Xb, rbase, kt2_, BUF, 0, 0);                                      \
        /* q3 */                                                                \
        PH_HEAD;  MMA_Q(1, 1, ba); LOAD_A((BUF) ^ 1, 0);        PRIO0;          \
        STAGE(Xb, rbase, kt2_, BUF, 0, 1);                                      \
    } while (0)

    for (int t = 0; t < NKT; t += 2) {
        KBODY(t, 0);
        KBODY(t + 1, 1);
    }

    // ---- fused LSTM epilogue (reg-resident, zero-shuffle) ----
    const int s = (nblk * 4 + wn) * 16 + l15;
    float bg[4];
    #pragma unroll
    for (int jj = 0; jj < 4; ++jj)
        bg[jj] = biasR[nbase + wn * 64 + jj * 16 + l15];

    #pragma unroll
    for (int mi = 0; mi < 8; ++mi) {
        #pragma unroll
        for (int r = 0; r < 4; ++r) {
            const int row = rbase + wm * 128 + mi * 16 + krow * 4 + r;
            float fg = sigm(acc[mi][0][r] + bg[0]);
            float ig = sigm(acc[mi][1][r] + bg[1]);
            float og = sigm(acc[mi][2][r] + bg[2]);
            float gg = tanh_fast(acc[mi][3][r] + bg[3]);
            float oc = old_cell[(size_t)row * SD + s];
            float nc = fmaf(fg, oc, ig * gg);
            float nh = og * tanh_fast(nc);
            new_h[(size_t)row * SD + s]    = nh;
            new_cell[(size_t)row * SD + s] = nc;
        }
    }
}

extern "C" void kernel_launch(void* const* d_in, const int* in_sizes, int n_in,
                              void* d_out, int out_size, void* d_ws, size_t ws_size,
                              hipStream_t stream) {
    const float* input    = (const float*)d_in[0];
    const float* old_h    = (const float*)d_in[1];
    const float* old_cell = (const float*)d_in[2];
    const float* weights  = (const float*)d_in[3];
    const float* bias     = (const float*)d_in[4];

    unsigned short* Xb  = (unsigned short*)d_ws;                             // 16 MiB
    unsigned short* Wb  = (unsigned short*)((char*)d_ws + (size_t)16777216); // 16 MiB
    float*          bR  = (float*)((char*)d_ws + (size_t)33554432);          // 16 KiB

    float* out_h = (float*)d_out;
    float* out_c = out_h + (size_t)NB * SD;

    pack_kernel<<<2048, 256, 0, stream>>>(input, old_h, weights, bias, Xb, Wb, bR);
    lstm_gemm<<<(NB / BM) * (ND / BN), 512, 0, stream>>>(Xb, Wb, bR, old_cell,
                                                         out_h, out_c);
}